// Round 15
// baseline (241.239 us; speedup 1.0000x reference)
//
#include <hip/hip_runtime.h>
#include <math.h>

#define NCOMP 32768
#define LDIM  128
#define HDIM  512
#define DDIM  256
#define BROWS 512
#define KTOP  16

// -0.5 * D * log(2*pi)
#define NEG_HALF_D_LOG2PI (-235.24844f)

typedef short bf16x8 __attribute__((ext_vector_type(8)));
typedef float f32x4  __attribute__((ext_vector_type(4)));
typedef unsigned short ushort_t;
typedef unsigned int uint_t;
typedef unsigned long long u64_t;

// ---------------- bf16 helpers (RNE) ----------------
__device__ __forceinline__ ushort_t f2bf(float f) {
  uint_t u = __float_as_uint(f);
  u = u + 0x7fffu + ((u >> 16) & 1u);
  return (ushort_t)(u >> 16);
}
__device__ __forceinline__ float bf2f(ushort_t h) {
  return __uint_as_float(((uint_t)h) << 16);
}

// async global->LDS, 16B per lane. LDS dest is wave-uniform base + lane*16.
__device__ __forceinline__ void load_lds16(const ushort_t* g, ushort_t* l) {
  __builtin_amdgcn_global_load_lds(
      (const __attribute__((address_space(1))) unsigned int*)g,
      (__attribute__((address_space(3))) unsigned int*)l, 16, 0, 0);
}

// ------------------------------------------------------------------
// Merged prep kernel (proven r11). Block ranges:
//  [0,4096)     cast z -> z16 bf16
//  [4096,4352)  W1 [128][512] -> W1t [512][128] bf16
//  [4352,5376)  W2 [512][512] -> W2t [512][512] bf16
//  [5376,5888)  x -> Xs [512][512] bf16: [x^2 (256) | x (256)]
// ------------------------------------------------------------------
__global__ __launch_bounds__(256) void prep_kernel(
    const float* __restrict__ x, const float* __restrict__ z,
    const float* __restrict__ W1, const float* __restrict__ W2,
    ushort_t* __restrict__ z16, ushort_t* __restrict__ W1t,
    ushort_t* __restrict__ W2t, ushort_t* __restrict__ Xs) {
  const int blk = blockIdx.x, tid = threadIdx.x;
  if (blk < 4096) {
    int i = (blk * 256 + tid) * 4;
    float4 v = *(const float4*)&z[i];
    z16[i + 0] = f2bf(v.x);
    z16[i + 1] = f2bf(v.y);
    z16[i + 2] = f2bf(v.z);
    z16[i + 3] = f2bf(v.w);
  } else if (blk < 4352) {
    int i = (blk - 4096) * 256 + tid;      // 128*512
    int r = i >> 9, c = i & 511;
    W1t[(size_t)c * 128 + r] = f2bf(W1[i]);
  } else if (blk < 5376) {
    int i = (blk - 4352) * 256 + tid;      // 512*512
    int r = i >> 9, c = i & 511;
    W2t[(size_t)c * 512 + r] = f2bf(W2[i]);
  } else {
    int i = (blk - 5376) * 256 + tid;      // 512*256
    int b = i >> 8, d = i & 255;
    float xv = x[i];
    size_t base = (size_t)b * 512;
    Xs[base + d]       = f2bf(xv * xv);
    Xs[base + 256 + d] = f2bf(xv);
  }
}

// raw [N][512] fp32 (mu | logvar) -> Ps [N][1024] bf16 : [hi(v) | lo(v)],
// v = [-0.5*inv_var (256), mu*inv_var (256)], plus
// cw[n] = cvec[n] + log_w[n]  (G3's bias -> G3 emits SCORES directly).
__global__ __launch_bounds__(256) void params_kernel(const float* __restrict__ raw,
                                                     const float* __restrict__ log_w,
                                                     ushort_t* __restrict__ Ps,
                                                     float* __restrict__ cw) {
  const int w = threadIdx.x >> 6, lane = threadIdx.x & 63;
  const int n = blockIdx.x * 4 + w;
  size_t rb = (size_t)n * 512;
  float4 mu4 = *(const float4*)(raw + rb + lane * 4);
  float4 lv4 = *(const float4*)(raw + rb + 256 + lane * 4);
  float mus[4] = {mu4.x, mu4.y, mu4.z, mu4.w};
  float lvs[4] = {lv4.x, lv4.y, lv4.z, lv4.w};
  ushort4 o0, o1, o2, o3;
  ushort_t* p0 = &o0.x; ushort_t* p1 = &o1.x;
  ushort_t* p2 = &o2.x; ushort_t* p3 = &o3.x;
  float part = 0.f;
  #pragma unroll
  for (int e = 0; e < 4; e++) {
    float lv = lvs[e];
    float sp = (lv > 20.f) ? lv : log1pf(expf(lv));
    float sd = fminf(sp + 0.1f, 1.0f);
    float iv = 1.0f / (sd * sd);
    float v0 = -0.5f * iv;
    float v1 = mus[e] * iv;
    ushort_t h0 = f2bf(v0), h1 = f2bf(v1);
    p0[e] = h0; p1[e] = h1;
    p2[e] = f2bf(v0 - bf2f(h0));
    p3[e] = f2bf(v1 - bf2f(h1));
    part += -0.5f * mus[e] * mus[e] * iv - logf(sd);
  }
  size_t pb = (size_t)n * 1024;
  *(ushort4*)(Ps + pb + lane * 4)       = o0;
  *(ushort4*)(Ps + pb + 256 + lane * 4) = o1;
  *(ushort4*)(Ps + pb + 512 + lane * 4) = o2;
  *(ushort4*)(Ps + pb + 768 + lane * 4) = o3;
  #pragma unroll
  for (int off = 32; off > 0; off >>= 1) part += __shfl_down(part, off, 64);
  if (lane == 0) cw[n] = part + NEG_HALF_D_LOG2PI + log_w[n];
}

// ------------------------------------------------------------------
// 128x128 bf16 MFMA GEMM — 2-phase loop at 2 blocks/CU (the correct
// quadrant per tile-space data: 128^2 for 2-barrier loops).
// BK=64, 256 threads (4 waves 2x2, each 64x64 = 4x4 frags), double-
// buffered 64KB LDS -> TWO independent barrier groups per CU: one
// block's vmcnt-drain overlaps the other's MFMA (m114 implicit overlap).
// Same proven 128B-row XOR swizzle / pre-swizzled global_load_lds
// source / kh-XOR fragment addressing as the r11 256^2 kernel.
// EPI: 0 = relu(+bias) -> bf16 out;  1 = +bias -> f32 out
// ------------------------------------------------------------------
template<int EPI>
__global__ __launch_bounds__(256, 2) void gemm128(
    const ushort_t* __restrict__ A, int lda,
    const ushort_t* __restrict__ B, int ldb,
    const float* __restrict__ bias,
    void* __restrict__ Cout, int ldc,
    int nsteps, int sps,
    int kbA0, int kbA1, int kbA2,
    int kbB0, int kbB1, int kbB2,
    int nShort, int shortIsM) {
  __shared__ __align__(16) ushort_t As[2][8192];   // 16KB per buffer
  __shared__ __align__(16) ushort_t Bs[2][8192];   // total 64KB -> 2 blk/CU

  const int tid = threadIdx.x;
  const int lane = tid & 63, wid = tid >> 6;
  const int wr = wid >> 1, wc = wid & 1;            // 2 x 2 wave grid

  // XCD-chunked bijective block swizzle (gridDim.x % 8 == 0)
  const int cpx = gridDim.x >> 3;
  const int newid = (blockIdx.x & 7) * cpx + (blockIdx.x >> 3);
  const int s = newid % nShort, l = newid / nShort;
  const int m0 = (shortIsM ? s : l) * 128;
  const int n0 = (shortIsM ? l : s) * 128;

  // ---- staging: 4 rounds per matrix; dest chunk p = r*256+tid (16B) ----
  // phys chunk p holds logical chunk (p&~7)|((p&7)^((p>>3)&7))
  const ushort_t* pA[4];
  const ushort_t* pB[4];
  #pragma unroll
  for (int r = 0; r < 4; r++) {
    int p = r * 256 + tid;
    int row = p >> 3;                       // 0..127
    int col = ((p & 7) ^ (row & 7)) * 8;
    pA[r] = A + (size_t)(m0 + row) * lda + col;
    pB[r] = B + (size_t)(n0 + row) * ldb + col;
  }

  // ---- fragment read byte-offsets (swizzled); k-half composed via XOR ----
  int aoff[4], boff[4];
  #pragma unroll
  for (int i = 0; i < 4; i++) {
    int ra = wr * 64 + i * 16 + (lane & 15);
    aoff[i] = (ra * 128 + ((lane >> 4) * 16)) ^ ((ra & 7) << 4);
  }
  #pragma unroll
  for (int j = 0; j < 4; j++) {
    int rb = wc * 64 + j * 16 + (lane & 15);
    boff[j] = (rb * 128 + ((lane >> 4) * 16)) ^ ((rb & 7) << 4);
  }

  f32x4 acc[4][4];
  #pragma unroll
  for (int i = 0; i < 4; i++)
    #pragma unroll
    for (int j = 0; j < 4; j++)
      acc[i][j] = (f32x4){0.f, 0.f, 0.f, 0.f};

  auto stage = [&](int buf, int step) {
    int sg = (step >= sps) ? ((step >= 2 * sps) ? 2 : 1) : 0;
    int ks = (step - sg * sps) << 6;
    int kA = ((sg == 0) ? kbA0 : (sg == 1) ? kbA1 : kbA2) + ks;
    int kB = ((sg == 0) ? kbB0 : (sg == 1) ? kbB1 : kbB2) + ks;
    #pragma unroll
    for (int r = 0; r < 4; r++) {
      load_lds16(pA[r] + kA, &As[buf][(r * 256 + tid) * 8]);
      load_lds16(pB[r] + kB, &Bs[buf][(r * 256 + tid) * 8]);
    }
  };

  stage(0, 0);
  __syncthreads();              // vmcnt drain -> buf0 ready

  int cur = 0;
  for (int step = 0; step < nsteps; ++step) {
    if (step + 1 < nsteps) stage(cur ^ 1, step + 1);   // loads fly over compute

    const char* Ab = (const char*)As[cur];
    const char* Bb = (const char*)Bs[cur];
    #pragma unroll
    for (int kh = 0; kh < 2; ++kh) {
      bf16x8 af[4], bfr[4];
      #pragma unroll
      for (int i = 0; i < 4; i++) af[i] = *(const bf16x8*)(Ab + (aoff[i] ^ (kh << 6)));
      #pragma unroll
      for (int j = 0; j < 4; j++) bfr[j] = *(const bf16x8*)(Bb + (boff[j] ^ (kh << 6)));
      #pragma unroll
      for (int i = 0; i < 4; i++)
        #pragma unroll
        for (int j = 0; j < 4; j++)
          acc[i][j] = __builtin_amdgcn_mfma_f32_16x16x32_bf16(af[i], bfr[j], acc[i][j], 0, 0, 0);
    }
    __syncthreads();            // drains vmcnt (next buf ready) + lgkm
    cur ^= 1;
  }

  // ---- epilogue ----
  float bv[4];
  #pragma unroll
  for (int j = 0; j < 4; j++)
    bv[j] = bias[n0 + wc * 64 + j * 16 + (lane & 15)];
  #pragma unroll
  for (int i = 0; i < 4; i++) {
    int rowb = m0 + wr * 64 + i * 16 + ((lane >> 4) << 2);
    #pragma unroll
    for (int r = 0; r < 4; r++) {
      #pragma unroll
      for (int j = 0; j < 4; j++) {
        int col = n0 + wc * 64 + j * 16 + (lane & 15);
        float v = acc[i][j][r] + bv[j];
        if (EPI == 0) {
          v = fmaxf(v, 0.f);
          ((ushort_t*)Cout)[(size_t)(rowb + r) * ldc + col] = f2bf(v);
        } else {
          ((float*)Cout)[(size_t)(rowb + r) * ldc + col] = v;
        }
      }
    }
  }
}

// ------------------------------------------------------------------
// Top-16 over precomputed scores (log_w folded into G3's bias).
// Wave-cooperative ballot-filtered select (proven). Output decodes the
// exact score from the key and subtracts log_w[idx] to recover lp.
// ------------------------------------------------------------------
__device__ __forceinline__ u64_t shfl_up1_u64(u64_t v) {
  uint_t lo = (uint_t)v, hi = (uint_t)(v >> 32);
  lo = __shfl_up(lo, 1, 64); hi = __shfl_up(hi, 1, 64);
  return ((u64_t)hi << 32) | lo;
}
__device__ __forceinline__ u64_t shfl_u64(u64_t v, int src) {
  uint_t lo = (uint_t)v, hi = (uint_t)(v >> 32);
  lo = __shfl(lo, src, 64); hi = __shfl(hi, src, 64);
  return ((u64_t)hi << 32) | lo;
}
__device__ __forceinline__ void insert_step(u64_t& key, u64_t cand, int lane) {
  u64_t kup = shfl_up1_u64(key);
  if (lane == 0) kup = ~0ULL;
  if (cand > key) key = (cand > kup) ? kup : cand;
}

__global__ __launch_bounds__(256) void topk_kernel(const float* __restrict__ sc,
                                                   const float* __restrict__ log_w,
                                                   float* __restrict__ out) {
  const int b = blockIdx.x;
  const int tid = threadIdx.x;
  const int w = tid >> 6, lane = tid & 63;
  const float* row = sc + (size_t)b * NCOMP;

  u64_t key = 0;
  u64_t theta = 0;

  const int base = w * 8192;
  float4 s4 = *(const float4*)&row[base + lane * 4];
  for (int c = 0; c < 32; ++c) {
    float4 cur = s4;
    int n0 = base + c * 256 + lane * 4;
    if (c + 1 < 32) s4 = *(const float4*)&row[n0 + 256];  // prefetch
    float ss[4] = {cur.x, cur.y, cur.z, cur.w};
    #pragma unroll
    for (int e = 0; e < 4; e++) {
      uint_t u = __float_as_uint(ss[e]);
      u = (u & 0x80000000u) ? ~u : (u | 0x80000000u);
      u64_t k = ((u64_t)u << 32) | (u64_t)(0xFFFFFFFFu - (uint_t)(n0 + e));
      u64_t m = __ballot(k > theta);
      if (m) {
        do {
          int src = __ffsll((long long)m) - 1;
          m &= m - 1;
          u64_t cand = shfl_u64(k, src);
          insert_step(key, cand, lane);
        } while (m);
        theta = shfl_u64(key, 15);
      }
    }
  }

  __shared__ u64_t sk[64];
  if (lane < 16) sk[w * 16 + lane] = key;
  __syncthreads();
  if (w == 0) {
    u64_t th = shfl_u64(key, 15);
    for (int t = 16; t < 64; ++t) {
      u64_t cand = sk[t];
      if (cand > th) {
        insert_step(key, cand, lane);
        th = shfl_u64(key, 15);
      }
    }
    if (lane < 16) {
      uint_t idx = 0xFFFFFFFFu - (uint_t)key;
      uint_t us = (uint_t)(key >> 32);
      us = (us & 0x80000000u) ? (us & 0x7FFFFFFFu) : ~us;   // decode score
      out[(size_t)b * KTOP + lane] = __uint_as_float(us) - log_w[idx];
    }
  }
}

// ------------------------------------------------------------------
extern "C" void kernel_launch(void* const* d_in, const int* in_sizes, int n_in,
                              void* d_out, int out_size, void* d_ws, size_t ws_size,
                              hipStream_t stream) {
  const float* x     = (const float*)d_in[0];
  const float* log_w = (const float*)d_in[1];
  const float* z     = (const float*)d_in[2];
  const float* W1    = (const float*)d_in[3];
  const float* b1    = (const float*)d_in[4];
  const float* W2    = (const float*)d_in[5];
  const float* b2    = (const float*)d_in[6];
  float* out = (float*)d_out;

  char* p = (char*)d_ws;
  float* raw   = (float*)p;    p += (size_t)NCOMP * 512 * 4;   // 64MB (reused as sc)
  float* cw    = (float*)p;    p += (size_t)NCOMP * 4;
  ushort_t* Ps = (ushort_t*)p; p += (size_t)NCOMP * 1024 * 2;  // 64MB
  ushort_t* h16= (ushort_t*)p; p += (size_t)NCOMP * 512 * 2;   // 32MB
  ushort_t* z16= (ushort_t*)p; p += (size_t)NCOMP * 128 * 2;   // 8MB
  ushort_t* W1t= (ushort_t*)p; p += (size_t)512 * 128 * 2;
  ushort_t* W2t= (ushort_t*)p; p += (size_t)512 * 512 * 2;
  ushort_t* Xs = (ushort_t*)p; p += (size_t)512 * 512 * 2;
  float* sc = raw;

  // prep (merged): z16, W1t, W2t, Xs
  hipLaunchKernelGGL(prep_kernel, dim3(5888), dim3(256), 0, stream,
                     x, z, W1, W2, z16, W1t, W2t, Xs);

  // G1: h16 = relu(z16 @ W1t^T + b1)  [32768,128]x[512,128]^T
  //     grid 256m x 4n = 1024; n fastest (siblings share A panel)
  hipLaunchKernelGGL((gemm128<0>), dim3(1024), dim3(256), 0, stream,
                     z16, LDIM, W1t, LDIM, b1, h16, HDIM,
                     2, 2, 0, 0, 0, 0, 0, 0, 4, 0);
  // G2: raw = h16 @ W2t^T + b2        [32768,512]x[512,512]^T
  hipLaunchKernelGGL((gemm128<1>), dim3(1024), dim3(256), 0, stream,
                     h16, HDIM, W2t, HDIM, b2, raw, HDIM,
                     8, 8, 0, 0, 0, 0, 0, 0, 4, 0);
  // params: raw -> Ps (split hi/lo), cw = cvec + log_w
  hipLaunchKernelGGL(params_kernel, dim3(NCOMP / 4), dim3(256), 0, stream,
                     raw, log_w, Ps, cw);
  // G3: sc = Xs @ Ps^T + cw  (split-bf16, A-lo dropped: uh*vh + uh*vl)
  //     K=1024: A segs {0,0} (hi,hi); B segs {0,512} (hi,lo); nt=16
  //     grid 4m x 256n = 1024; m fastest (siblings share B panel)
  hipLaunchKernelGGL((gemm128<1>), dim3(1024), dim3(256), 0, stream,
                     Xs, 512, Ps, 1024, cw, sc, NCOMP,
                     16, 8, 0, 0, 0, 0, 512, 0, 4, 1);
  // topk over scores; output lp = score - log_w[idx]
  hipLaunchKernelGGL(topk_kernel, dim3(BROWS), dim3(256), 0, stream, sc, log_w, out);
}

// Round 16
// 199.877 us; speedup vs baseline: 1.2069x; 1.2069x over previous
//
#include <hip/hip_runtime.h>
#include <math.h>

#define NCOMP 32768
#define LDIM  128
#define HDIM  512
#define DDIM  256
#define BROWS 512
#define KTOP  16

// -0.5 * D * log(2*pi)
#define NEG_HALF_D_LOG2PI (-235.24844f)

typedef short bf16x8 __attribute__((ext_vector_type(8)));
typedef float f32x4  __attribute__((ext_vector_type(4)));
typedef unsigned short ushort_t;
typedef unsigned int uint_t;
typedef unsigned long long u64_t;

// ---------------- bf16 helpers (RNE) ----------------
__device__ __forceinline__ ushort_t f2bf(float f) {
  uint_t u = __float_as_uint(f);
  u = u + 0x7fffu + ((u >> 16) & 1u);
  return (ushort_t)(u >> 16);
}
__device__ __forceinline__ float bf2f(ushort_t h) {
  return __uint_as_float(((uint_t)h) << 16);
}

// async global->LDS, 16B per lane. LDS dest is wave-uniform base + lane*16.
__device__ __forceinline__ void load_lds16(const ushort_t* g, ushort_t* l) {
  __builtin_amdgcn_global_load_lds(
      (const __attribute__((address_space(1))) unsigned int*)g,
      (__attribute__((address_space(3))) unsigned int*)l, 16, 0, 0);
}

// ------------------------------------------------------------------
// Merged prep kernel (proven r11). Block ranges:
//  [0,4096)     cast z -> z16 bf16
//  [4096,4352)  W1 [128][512] -> W1t [512][128] bf16
//  [4352,5376)  W2 [512][512] -> W2t [512][512] bf16
//  [5376,5888)  x -> Xs [512][512] bf16: [x^2 (256) | x (256)]
// ------------------------------------------------------------------
__global__ __launch_bounds__(256) void prep_kernel(
    const float* __restrict__ x, const float* __restrict__ z,
    const float* __restrict__ W1, const float* __restrict__ W2,
    ushort_t* __restrict__ z16, ushort_t* __restrict__ W1t,
    ushort_t* __restrict__ W2t, ushort_t* __restrict__ Xs) {
  const int blk = blockIdx.x, tid = threadIdx.x;
  if (blk < 4096) {
    int i = (blk * 256 + tid) * 4;
    float4 v = *(const float4*)&z[i];
    z16[i + 0] = f2bf(v.x);
    z16[i + 1] = f2bf(v.y);
    z16[i + 2] = f2bf(v.z);
    z16[i + 3] = f2bf(v.w);
  } else if (blk < 4352) {
    int i = (blk - 4096) * 256 + tid;      // 128*512
    int r = i >> 9, c = i & 511;
    W1t[(size_t)c * 128 + r] = f2bf(W1[i]);
  } else if (blk < 5376) {
    int i = (blk - 4352) * 256 + tid;      // 512*512
    int r = i >> 9, c = i & 511;
    W2t[(size_t)c * 512 + r] = f2bf(W2[i]);
  } else {
    int i = (blk - 5376) * 256 + tid;      // 512*256
    int b = i >> 8, d = i & 255;
    float xv = x[i];
    size_t base = (size_t)b * 512;
    Xs[base + d]       = f2bf(xv * xv);
    Xs[base + 256 + d] = f2bf(xv);
  }
}

// raw [N][512] fp32 (mu | logvar) -> Ps [N][1024] bf16 : [hi(v) | lo(v)],
// v = [-0.5*inv_var (256), mu*inv_var (256)], plus
// cw[n] = cvec[n] + log_w[n]  (G3's bias -> G3 emits SCORES directly).
__global__ __launch_bounds__(256) void params_kernel(const float* __restrict__ raw,
                                                     const float* __restrict__ log_w,
                                                     ushort_t* __restrict__ Ps,
                                                     float* __restrict__ cw) {
  const int w = threadIdx.x >> 6, lane = threadIdx.x & 63;
  const int n = blockIdx.x * 4 + w;
  size_t rb = (size_t)n * 512;
  float4 mu4 = *(const float4*)(raw + rb + lane * 4);
  float4 lv4 = *(const float4*)(raw + rb + 256 + lane * 4);
  float mus[4] = {mu4.x, mu4.y, mu4.z, mu4.w};
  float lvs[4] = {lv4.x, lv4.y, lv4.z, lv4.w};
  ushort4 o0, o1, o2, o3;
  ushort_t* p0 = &o0.x; ushort_t* p1 = &o1.x;
  ushort_t* p2 = &o2.x; ushort_t* p3 = &o3.x;
  float part = 0.f;
  #pragma unroll
  for (int e = 0; e < 4; e++) {
    float lv = lvs[e];
    float sp = (lv > 20.f) ? lv : log1pf(expf(lv));
    float sd = fminf(sp + 0.1f, 1.0f);
    float iv = 1.0f / (sd * sd);
    float v0 = -0.5f * iv;
    float v1 = mus[e] * iv;
    ushort_t h0 = f2bf(v0), h1 = f2bf(v1);
    p0[e] = h0; p1[e] = h1;
    p2[e] = f2bf(v0 - bf2f(h0));
    p3[e] = f2bf(v1 - bf2f(h1));
    part += -0.5f * mus[e] * mus[e] * iv - logf(sd);
  }
  size_t pb = (size_t)n * 1024;
  *(ushort4*)(Ps + pb + lane * 4)       = o0;
  *(ushort4*)(Ps + pb + 256 + lane * 4) = o1;
  *(ushort4*)(Ps + pb + 512 + lane * 4) = o2;
  *(ushort4*)(Ps + pb + 768 + lane * 4) = o3;
  #pragma unroll
  for (int off = 32; off > 0; off >>= 1) part += __shfl_down(part, off, 64);
  if (lane == 0) cw[n] = part + NEG_HALF_D_LOG2PI + log_w[n];
}

// ------------------------------------------------------------------
// 256x256 bf16 MFMA GEMM — r11/r14 2-phase structure. PROVEN OPTIMUM
// for this problem: r7 8-phase (-35%), r12 BK=32 (-14%), r13 asym-depth
// (-19%), r15 128^2 tile (-38%) all regressed. Grid = 256 = CU count
// with 8 barrier-locked waves -> no wave-slip for deeper pipelines;
// 256^2 maximizes arithmetic intensity (FLOP/staged-byte = 128).
// BK=64, 512 threads (8 waves 2x4), double-buffered 128KB LDS,
// global_load_lds 16B with pre-swizzled source, XOR swizzle, k-half
// composed via XOR. One __syncthreads per K-step.
// EPI: 0 = relu(+bias) -> bf16 out;  1 = +bias -> f32 out
// ------------------------------------------------------------------
template<int EPI>
__global__ __launch_bounds__(512, 2) void gemm256(
    const ushort_t* __restrict__ A, int lda,
    const ushort_t* __restrict__ B, int ldb,
    const float* __restrict__ bias,
    void* __restrict__ Cout, int ldc,
    int nsteps, int sps,
    int kbA0, int kbA1, int kbA2,
    int kbB0, int kbB1, int kbB2,
    int nShort, int shortIsM) {
  __shared__ __align__(16) ushort_t As[2][16384];   // 32KB per buffer
  __shared__ __align__(16) ushort_t Bs[2][16384];

  const int tid = threadIdx.x;
  const int lane = tid & 63, wid = tid >> 6;
  const int wr = wid >> 2, wc = wid & 3;            // 2 x 4 wave grid

  // XCD-chunked bijective block swizzle (gridDim.x % 8 == 0)
  const int cpx = gridDim.x >> 3;
  const int newid = (blockIdx.x & 7) * cpx + (blockIdx.x >> 3);
  const int s = newid % nShort, l = newid / nShort;
  const int m0 = (shortIsM ? s : l) * 256;
  const int n0 = (shortIsM ? l : s) * 256;

  // ---- staging: 4 rounds per matrix; dest chunk p = r*512+tid (16B) ----
  const ushort_t* pA[4];
  const ushort_t* pB[4];
  #pragma unroll
  for (int r = 0; r < 4; r++) {
    int p = r * 512 + tid;
    int row = p >> 3;
    int col = ((p & 7) ^ (row & 7)) * 8;
    pA[r] = A + (size_t)(m0 + row) * lda + col;
    pB[r] = B + (size_t)(n0 + row) * ldb + col;
  }

  // ---- fragment read byte-offsets (swizzled); k-half composed via XOR ----
  int aoff[8], boff[4];
  #pragma unroll
  for (int i = 0; i < 8; i++) {
    int ra = wr * 128 + i * 16 + (lane & 15);
    aoff[i] = (ra * 128 + ((lane >> 4) * 16)) ^ ((ra & 7) << 4);
  }
  #pragma unroll
  for (int j = 0; j < 4; j++) {
    int rb = wc * 64 + j * 16 + (lane & 15);
    boff[j] = (rb * 128 + ((lane >> 4) * 16)) ^ ((rb & 7) << 4);
  }

  f32x4 acc[8][4];
  #pragma unroll
  for (int i = 0; i < 8; i++)
    #pragma unroll
    for (int j = 0; j < 4; j++)
      acc[i][j] = (f32x4){0.f, 0.f, 0.f, 0.f};

  auto stage = [&](int buf, int step) {
    int sg = (step >= sps) ? ((step >= 2 * sps) ? 2 : 1) : 0;
    int ks = (step - sg * sps) << 6;
    int kA = ((sg == 0) ? kbA0 : (sg == 1) ? kbA1 : kbA2) + ks;
    int kB = ((sg == 0) ? kbB0 : (sg == 1) ? kbB1 : kbB2) + ks;
    #pragma unroll
    for (int r = 0; r < 4; r++) {
      load_lds16(pA[r] + kA, &As[buf][(r * 512 + tid) * 8]);
      load_lds16(pB[r] + kB, &Bs[buf][(r * 512 + tid) * 8]);
    }
  };

  stage(0, 0);
  __syncthreads();              // vmcnt drain -> buf0 ready

  int cur = 0;
  for (int step = 0; step < nsteps; ++step) {
    if (step + 1 < nsteps) stage(cur ^ 1, step + 1);   // loads fly over compute

    const char* Ab = (const char*)As[cur];
    const char* Bb = (const char*)Bs[cur];
    #pragma unroll
    for (int kh = 0; kh < 2; ++kh) {
      bf16x8 af[8], bfr[4];
      #pragma unroll
      for (int i = 0; i < 8; i++) af[i] = *(const bf16x8*)(Ab + (aoff[i] ^ (kh << 6)));
      #pragma unroll
      for (int j = 0; j < 4; j++) bfr[j] = *(const bf16x8*)(Bb + (boff[j] ^ (kh << 6)));
      #pragma unroll
      for (int i = 0; i < 8; i++)
        #pragma unroll
        for (int j = 0; j < 4; j++)
          acc[i][j] = __builtin_amdgcn_mfma_f32_16x16x32_bf16(af[i], bfr[j], acc[i][j], 0, 0, 0);
    }
    __syncthreads();            // drains vmcnt (next buf ready) + lgkm
    cur ^= 1;
  }

  // ---- epilogue ----
  float bv[4];
  #pragma unroll
  for (int j = 0; j < 4; j++)
    bv[j] = bias[n0 + wc * 64 + j * 16 + (lane & 15)];
  #pragma unroll
  for (int i = 0; i < 8; i++) {
    int rowb = m0 + wr * 128 + i * 16 + ((lane >> 4) << 2);
    #pragma unroll
    for (int r = 0; r < 4; r++) {
      #pragma unroll
      for (int j = 0; j < 4; j++) {
        int col = n0 + wc * 64 + j * 16 + (lane & 15);
        float v = acc[i][j][r] + bv[j];
        if (EPI == 0) {
          v = fmaxf(v, 0.f);
          ((ushort_t*)Cout)[(size_t)(rowb + r) * ldc + col] = f2bf(v);
        } else {
          ((float*)Cout)[(size_t)(rowb + r) * ldc + col] = v;
        }
      }
    }
  }
}

// ------------------------------------------------------------------
// Top-16 over precomputed scores (lp + log_w already folded in G3).
// Wave-cooperative ballot-filtered select; key = sortable(score)<<32 |
// (~idx) -> ties pick lower index (== jax.lax.top_k). Output decodes
// the exact score from the key and subtracts log_w[idx] to recover lp.
// Software prefetch of the next float4 hides load latency under the
// ballot/insert work.
// ------------------------------------------------------------------
__device__ __forceinline__ u64_t shfl_up1_u64(u64_t v) {
  uint_t lo = (uint_t)v, hi = (uint_t)(v >> 32);
  lo = __shfl_up(lo, 1, 64); hi = __shfl_up(hi, 1, 64);
  return ((u64_t)hi << 32) | lo;
}
__device__ __forceinline__ u64_t shfl_u64(u64_t v, int src) {
  uint_t lo = (uint_t)v, hi = (uint_t)(v >> 32);
  lo = __shfl(lo, src, 64); hi = __shfl(hi, src, 64);
  return ((u64_t)hi << 32) | lo;
}
__device__ __forceinline__ void insert_step(u64_t& key, u64_t cand, int lane) {
  u64_t kup = shfl_up1_u64(key);
  if (lane == 0) kup = ~0ULL;
  if (cand > key) key = (cand > kup) ? kup : cand;
}

__global__ __launch_bounds__(256) void topk_kernel(const float* __restrict__ sc,
                                                   const float* __restrict__ log_w,
                                                   float* __restrict__ out) {
  const int b = blockIdx.x;
  const int tid = threadIdx.x;
  const int w = tid >> 6, lane = tid & 63;
  const float* row = sc + (size_t)b * NCOMP;

  u64_t key = 0;
  u64_t theta = 0;

  const int base = w * 8192;
  float4 s4 = *(const float4*)&row[base + lane * 4];
  for (int c = 0; c < 32; ++c) {
    float4 cur = s4;
    int n0 = base + c * 256 + lane * 4;
    if (c + 1 < 32) s4 = *(const float4*)&row[n0 + 256];  // prefetch
    float ss[4] = {cur.x, cur.y, cur.z, cur.w};
    #pragma unroll
    for (int e = 0; e < 4; e++) {
      uint_t u = __float_as_uint(ss[e]);
      u = (u & 0x80000000u) ? ~u : (u | 0x80000000u);
      u64_t k = ((u64_t)u << 32) | (u64_t)(0xFFFFFFFFu - (uint_t)(n0 + e));
      u64_t m = __ballot(k > theta);
      if (m) {
        do {
          int src = __ffsll((long long)m) - 1;
          m &= m - 1;
          u64_t cand = shfl_u64(k, src);
          insert_step(key, cand, lane);
        } while (m);
        theta = shfl_u64(key, 15);
      }
    }
  }

  __shared__ u64_t sk[64];
  if (lane < 16) sk[w * 16 + lane] = key;
  __syncthreads();
  if (w == 0) {
    u64_t th = shfl_u64(key, 15);
    for (int t = 16; t < 64; ++t) {
      u64_t cand = sk[t];
      if (cand > th) {
        insert_step(key, cand, lane);
        th = shfl_u64(key, 15);
      }
    }
    if (lane < 16) {
      uint_t idx = 0xFFFFFFFFu - (uint_t)key;
      uint_t us = (uint_t)(key >> 32);
      us = (us & 0x80000000u) ? (us & 0x7FFFFFFFu) : ~us;   // decode score
      out[(size_t)b * KTOP + lane] = __uint_as_float(us) - log_w[idx];
    }
  }
}

// ------------------------------------------------------------------
extern "C" void kernel_launch(void* const* d_in, const int* in_sizes, int n_in,
                              void* d_out, int out_size, void* d_ws, size_t ws_size,
                              hipStream_t stream) {
  const float* x     = (const float*)d_in[0];
  const float* log_w = (const float*)d_in[1];
  const float* z     = (const float*)d_in[2];
  const float* W1    = (const float*)d_in[3];
  const float* b1    = (const float*)d_in[4];
  const float* W2    = (const float*)d_in[5];
  const float* b2    = (const float*)d_in[6];
  float* out = (float*)d_out;

  char* p = (char*)d_ws;
  float* raw   = (float*)p;    p += (size_t)NCOMP * 512 * 4;   // 64MB (reused as sc)
  float* cw    = (float*)p;    p += (size_t)NCOMP * 4;
  ushort_t* Ps = (ushort_t*)p; p += (size_t)NCOMP * 1024 * 2;  // 64MB
  ushort_t* h16= (ushort_t*)p; p += (size_t)NCOMP * 512 * 2;   // 32MB
  ushort_t* z16= (ushort_t*)p; p += (size_t)NCOMP * 128 * 2;   // 8MB
  ushort_t* W1t= (ushort_t*)p; p += (size_t)512 * 128 * 2;
  ushort_t* W2t= (ushort_t*)p; p += (size_t)512 * 512 * 2;
  ushort_t* Xs = (ushort_t*)p; p += (size_t)512 * 512 * 2;
  float* sc = raw;

  // prep (merged): z16, W1t, W2t, Xs
  hipLaunchKernelGGL(prep_kernel, dim3(5888), dim3(256), 0, stream,
                     x, z, W1, W2, z16, W1t, W2t, Xs);

  // G1: h16 = relu(z16 @ W1t^T + b1)   [32768,128] x [512,128]^T
  hipLaunchKernelGGL((gemm256<0>), dim3(256), dim3(512), 0, stream,
                     z16, LDIM, W1t, LDIM, b1, h16, HDIM,
                     2, 2, 0, 0, 0, 0, 0, 0, 2, 0);
  // G2: raw = h16 @ W2t^T + b2         [32768,512] x [512,512]^T
  hipLaunchKernelGGL((gemm256<1>), dim3(256), dim3(512), 0, stream,
                     h16, HDIM, W2t, HDIM, b2, raw, HDIM,
                     8, 8, 0, 0, 0, 0, 0, 0, 2, 0);
  // params: raw -> Ps (split hi/lo), cw = cvec + log_w
  hipLaunchKernelGGL(params_kernel, dim3(NCOMP / 4), dim3(256), 0, stream,
                     raw, log_w, Ps, cw);
  // G3: sc = Xs @ Ps^T + cw  (split-bf16, A-lo dropped: uh*vh + uh*vl)
  //     K=1024: A segs {0,0} (hi,hi); B segs {0,512} (hi,lo); nt=16
  hipLaunchKernelGGL((gemm256<1>), dim3(256), dim3(512), 0, stream,
                     Xs, 512, Ps, 1024, cw, sc, NCOMP,
                     16, 8, 0, 0, 0, 0, 512, 0, 2, 1);
  // topk over scores; output lp = score - log_w[idx]
  hipLaunchKernelGGL(topk_kernel, dim3(BROWS), dim3(256), 0, stream, sc, log_w, out);
}

// Round 17
// 196.871 us; speedup vs baseline: 1.2254x; 1.0153x over previous
//
#include <hip/hip_runtime.h>
#include <math.h>

#define NCOMP 32768
#define LDIM  128
#define HDIM  512
#define DDIM  256
#define BROWS 512
#define KTOP  16

// -0.5 * D * log(2*pi)
#define NEG_HALF_D_LOG2PI (-235.24844f)

typedef short bf16x8 __attribute__((ext_vector_type(8)));
typedef float f32x4  __attribute__((ext_vector_type(4)));
typedef unsigned short ushort_t;
typedef unsigned int uint_t;
typedef unsigned long long u64_t;

// ---------------- bf16 helpers (RNE) ----------------
__device__ __forceinline__ ushort_t f2bf(float f) {
  uint_t u = __float_as_uint(f);
  u = u + 0x7fffu + ((u >> 16) & 1u);
  return (ushort_t)(u >> 16);
}
__device__ __forceinline__ float bf2f(ushort_t h) {
  return __uint_as_float(((uint_t)h) << 16);
}

// async global->LDS, 16B per lane. LDS dest is wave-uniform base + lane*16.
__device__ __forceinline__ void load_lds16(const ushort_t* g, ushort_t* l) {
  __builtin_amdgcn_global_load_lds(
      (const __attribute__((address_space(1))) unsigned int*)g,
      (__attribute__((address_space(3))) unsigned int*)l, 16, 0, 0);
}

// ------------------------------------------------------------------
// Merged prep kernel (proven r11). Block ranges:
//  [0,4096)     cast z -> z16 bf16
//  [4096,4352)  W1 [128][512] -> W1t [512][128] bf16
//  [4352,5376)  W2 [512][512] -> W2t [512][512] bf16
//  [5376,5888)  x -> Xs [512][512] bf16: [x^2 (256) | x (256)]
// ------------------------------------------------------------------
__global__ __launch_bounds__(256) void prep_kernel(
    const float* __restrict__ x, const float* __restrict__ z,
    const float* __restrict__ W1, const float* __restrict__ W2,
    ushort_t* __restrict__ z16, ushort_t* __restrict__ W1t,
    ushort_t* __restrict__ W2t, ushort_t* __restrict__ Xs) {
  const int blk = blockIdx.x, tid = threadIdx.x;
  if (blk < 4096) {
    int i = (blk * 256 + tid) * 4;
    float4 v = *(const float4*)&z[i];
    z16[i + 0] = f2bf(v.x);
    z16[i + 1] = f2bf(v.y);
    z16[i + 2] = f2bf(v.z);
    z16[i + 3] = f2bf(v.w);
  } else if (blk < 4352) {
    int i = (blk - 4096) * 256 + tid;      // 128*512
    int r = i >> 9, c = i & 511;
    W1t[(size_t)c * 128 + r] = f2bf(W1[i]);
  } else if (blk < 5376) {
    int i = (blk - 4352) * 256 + tid;      // 512*512
    int r = i >> 9, c = i & 511;
    W2t[(size_t)c * 512 + r] = f2bf(W2[i]);
  } else {
    int i = (blk - 5376) * 256 + tid;      // 512*256
    int b = i >> 8, d = i & 255;
    float xv = x[i];
    size_t base = (size_t)b * 512;
    Xs[base + d]       = f2bf(xv * xv);
    Xs[base + 256 + d] = f2bf(xv);
  }
}

// rawb [N][512] bf16 (mu | logvar) -> Ps [N][1024] bf16 : [hi(v) | lo(v)],
// v = [-0.5*inv_var (256), mu*inv_var (256)], plus
// cw[n] = cvec[n] + log_w[n]  (G3's bias -> G3 emits SCORES directly).
// Input is bf16 (G2 EPI=3): rounded mu/logvar used CONSISTENTLY in both
// Ps and cvec -> computed score is the exact score of the bf16-param
// Gaussian (error ~1 absolute vs f32 path; threshold headroom 4.9).
__global__ __launch_bounds__(256) void params_kernel(const ushort_t* __restrict__ rawb,
                                                     const float* __restrict__ log_w,
                                                     ushort_t* __restrict__ Ps,
                                                     float* __restrict__ cw) {
  const int w = threadIdx.x >> 6, lane = threadIdx.x & 63;
  const int n = blockIdx.x * 4 + w;
  size_t rb = (size_t)n * 512;
  ushort4 mu4 = *(const ushort4*)(rawb + rb + lane * 4);
  ushort4 lv4 = *(const ushort4*)(rawb + rb + 256 + lane * 4);
  float mus[4] = {bf2f(mu4.x), bf2f(mu4.y), bf2f(mu4.z), bf2f(mu4.w)};
  float lvs[4] = {bf2f(lv4.x), bf2f(lv4.y), bf2f(lv4.z), bf2f(lv4.w)};
  ushort4 o0, o1, o2, o3;
  ushort_t* p0 = &o0.x; ushort_t* p1 = &o1.x;
  ushort_t* p2 = &o2.x; ushort_t* p3 = &o3.x;
  float part = 0.f;
  #pragma unroll
  for (int e = 0; e < 4; e++) {
    float lv = lvs[e];
    float sp = (lv > 20.f) ? lv : log1pf(expf(lv));
    float sd = fminf(sp + 0.1f, 1.0f);
    float iv = 1.0f / (sd * sd);
    float v0 = -0.5f * iv;
    float v1 = mus[e] * iv;
    ushort_t h0 = f2bf(v0), h1 = f2bf(v1);
    p0[e] = h0; p1[e] = h1;
    p2[e] = f2bf(v0 - bf2f(h0));
    p3[e] = f2bf(v1 - bf2f(h1));
    part += -0.5f * mus[e] * mus[e] * iv - logf(sd);
  }
  size_t pb = (size_t)n * 1024;
  *(ushort4*)(Ps + pb + lane * 4)       = o0;
  *(ushort4*)(Ps + pb + 256 + lane * 4) = o1;
  *(ushort4*)(Ps + pb + 512 + lane * 4) = o2;
  *(ushort4*)(Ps + pb + 768 + lane * 4) = o3;
  #pragma unroll
  for (int off = 32; off > 0; off >>= 1) part += __shfl_down(part, off, 64);
  if (lane == 0) cw[n] = part + NEG_HALF_D_LOG2PI + log_w[n];
}

// ------------------------------------------------------------------
// 256x256 bf16 MFMA GEMM — r11/r14 2-phase structure. PROVEN OPTIMUM
// for this problem: r7 8-phase (-35%), r12 BK=32 (-14%), r13 asym-depth
// (-19%), r15 128^2 tile (-38%) all regressed. Grid = 256 = CU count
// with 8 barrier-locked waves -> no wave-slip for deeper pipelines;
// 256^2 maximizes arithmetic intensity (FLOP/staged-byte = 128).
// BK=64, 512 threads (8 waves 2x4), double-buffered 128KB LDS,
// global_load_lds 16B with pre-swizzled source, XOR swizzle, k-half
// composed via XOR. One __syncthreads per K-step.
// EPI: 0 = relu(+bias) -> bf16; 1 = +bias -> f32; 3 = +bias -> bf16
// ------------------------------------------------------------------
template<int EPI>
__global__ __launch_bounds__(512, 2) void gemm256(
    const ushort_t* __restrict__ A, int lda,
    const ushort_t* __restrict__ B, int ldb,
    const float* __restrict__ bias,
    void* __restrict__ Cout, int ldc,
    int nsteps, int sps,
    int kbA0, int kbA1, int kbA2,
    int kbB0, int kbB1, int kbB2,
    int nShort, int shortIsM) {
  __shared__ __align__(16) ushort_t As[2][16384];   // 32KB per buffer
  __shared__ __align__(16) ushort_t Bs[2][16384];

  const int tid = threadIdx.x;
  const int lane = tid & 63, wid = tid >> 6;
  const int wr = wid >> 2, wc = wid & 3;            // 2 x 4 wave grid

  // XCD-chunked bijective block swizzle (gridDim.x % 8 == 0)
  const int cpx = gridDim.x >> 3;
  const int newid = (blockIdx.x & 7) * cpx + (blockIdx.x >> 3);
  const int s = newid % nShort, l = newid / nShort;
  const int m0 = (shortIsM ? s : l) * 256;
  const int n0 = (shortIsM ? l : s) * 256;

  // ---- staging: 4 rounds per matrix; dest chunk p = r*512+tid (16B) ----
  const ushort_t* pA[4];
  const ushort_t* pB[4];
  #pragma unroll
  for (int r = 0; r < 4; r++) {
    int p = r * 512 + tid;
    int row = p >> 3;
    int col = ((p & 7) ^ (row & 7)) * 8;
    pA[r] = A + (size_t)(m0 + row) * lda + col;
    pB[r] = B + (size_t)(n0 + row) * ldb + col;
  }

  // ---- fragment read byte-offsets (swizzled); k-half composed via XOR ----
  int aoff[8], boff[4];
  #pragma unroll
  for (int i = 0; i < 8; i++) {
    int ra = wr * 128 + i * 16 + (lane & 15);
    aoff[i] = (ra * 128 + ((lane >> 4) * 16)) ^ ((ra & 7) << 4);
  }
  #pragma unroll
  for (int j = 0; j < 4; j++) {
    int rb = wc * 64 + j * 16 + (lane & 15);
    boff[j] = (rb * 128 + ((lane >> 4) * 16)) ^ ((rb & 7) << 4);
  }

  f32x4 acc[8][4];
  #pragma unroll
  for (int i = 0; i < 8; i++)
    #pragma unroll
    for (int j = 0; j < 4; j++)
      acc[i][j] = (f32x4){0.f, 0.f, 0.f, 0.f};

  auto stage = [&](int buf, int step) {
    int sg = (step >= sps) ? ((step >= 2 * sps) ? 2 : 1) : 0;
    int ks = (step - sg * sps) << 6;
    int kA = ((sg == 0) ? kbA0 : (sg == 1) ? kbA1 : kbA2) + ks;
    int kB = ((sg == 0) ? kbB0 : (sg == 1) ? kbB1 : kbB2) + ks;
    #pragma unroll
    for (int r = 0; r < 4; r++) {
      load_lds16(pA[r] + kA, &As[buf][(r * 512 + tid) * 8]);
      load_lds16(pB[r] + kB, &Bs[buf][(r * 512 + tid) * 8]);
    }
  };

  stage(0, 0);
  __syncthreads();              // vmcnt drain -> buf0 ready

  int cur = 0;
  for (int step = 0; step < nsteps; ++step) {
    if (step + 1 < nsteps) stage(cur ^ 1, step + 1);   // loads fly over compute

    const char* Ab = (const char*)As[cur];
    const char* Bb = (const char*)Bs[cur];
    #pragma unroll
    for (int kh = 0; kh < 2; ++kh) {
      bf16x8 af[8], bfr[4];
      #pragma unroll
      for (int i = 0; i < 8; i++) af[i] = *(const bf16x8*)(Ab + (aoff[i] ^ (kh << 6)));
      #pragma unroll
      for (int j = 0; j < 4; j++) bfr[j] = *(const bf16x8*)(Bb + (boff[j] ^ (kh << 6)));
      #pragma unroll
      for (int i = 0; i < 8; i++)
        #pragma unroll
        for (int j = 0; j < 4; j++)
          acc[i][j] = __builtin_amdgcn_mfma_f32_16x16x32_bf16(af[i], bfr[j], acc[i][j], 0, 0, 0);
    }
    __syncthreads();            // drains vmcnt (next buf ready) + lgkm
    cur ^= 1;
  }

  // ---- epilogue ----
  float bv[4];
  #pragma unroll
  for (int j = 0; j < 4; j++)
    bv[j] = bias[n0 + wc * 64 + j * 16 + (lane & 15)];
  #pragma unroll
  for (int i = 0; i < 8; i++) {
    int rowb = m0 + wr * 128 + i * 16 + ((lane >> 4) << 2);
    #pragma unroll
    for (int r = 0; r < 4; r++) {
      #pragma unroll
      for (int j = 0; j < 4; j++) {
        int col = n0 + wc * 64 + j * 16 + (lane & 15);
        float v = acc[i][j][r] + bv[j];
        if (EPI == 0) {
          v = fmaxf(v, 0.f);
          ((ushort_t*)Cout)[(size_t)(rowb + r) * ldc + col] = f2bf(v);
        } else if (EPI == 3) {
          ((ushort_t*)Cout)[(size_t)(rowb + r) * ldc + col] = f2bf(v);
        } else {
          ((float*)Cout)[(size_t)(rowb + r) * ldc + col] = v;
        }
      }
    }
  }
}

// ------------------------------------------------------------------
// Top-16 over precomputed scores (lp + log_w already folded in G3).
// Wave-cooperative ballot-filtered select; key = sortable(score)<<32 |
// (~idx) -> ties pick lower index (== jax.lax.top_k). Output decodes
// the exact score from the key and subtracts log_w[idx] to recover lp.
// ------------------------------------------------------------------
__device__ __forceinline__ u64_t shfl_up1_u64(u64_t v) {
  uint_t lo = (uint_t)v, hi = (uint_t)(v >> 32);
  lo = __shfl_up(lo, 1, 64); hi = __shfl_up(hi, 1, 64);
  return ((u64_t)hi << 32) | lo;
}
__device__ __forceinline__ u64_t shfl_u64(u64_t v, int src) {
  uint_t lo = (uint_t)v, hi = (uint_t)(v >> 32);
  lo = __shfl(lo, src, 64); hi = __shfl(hi, src, 64);
  return ((u64_t)hi << 32) | lo;
}
__device__ __forceinline__ void insert_step(u64_t& key, u64_t cand, int lane) {
  u64_t kup = shfl_up1_u64(key);
  if (lane == 0) kup = ~0ULL;
  if (cand > key) key = (cand > kup) ? kup : cand;
}

__global__ __launch_bounds__(256) void topk_kernel(const float* __restrict__ sc,
                                                   const float* __restrict__ log_w,
                                                   float* __restrict__ out) {
  const int b = blockIdx.x;
  const int tid = threadIdx.x;
  const int w = tid >> 6, lane = tid & 63;
  const float* row = sc + (size_t)b * NCOMP;

  u64_t key = 0;
  u64_t theta = 0;

  const int base = w * 8192;
  float4 s4 = *(const float4*)&row[base + lane * 4];
  for (int c = 0; c < 32; ++c) {
    float4 cur = s4;
    int n0 = base + c * 256 + lane * 4;
    if (c + 1 < 32) s4 = *(const float4*)&row[n0 + 256];  // prefetch
    float ss[4] = {cur.x, cur.y, cur.z, cur.w};
    #pragma unroll
    for (int e = 0; e < 4; e++) {
      uint_t u = __float_as_uint(ss[e]);
      u = (u & 0x80000000u) ? ~u : (u | 0x80000000u);
      u64_t k = ((u64_t)u << 32) | (u64_t)(0xFFFFFFFFu - (uint_t)(n0 + e));
      u64_t m = __ballot(k > theta);
      if (m) {
        do {
          int src = __ffsll((long long)m) - 1;
          m &= m - 1;
          u64_t cand = shfl_u64(k, src);
          insert_step(key, cand, lane);
        } while (m);
        theta = shfl_u64(key, 15);
      }
    }
  }

  __shared__ u64_t sk[64];
  if (lane < 16) sk[w * 16 + lane] = key;
  __syncthreads();
  if (w == 0) {
    u64_t th = shfl_u64(key, 15);
    for (int t = 16; t < 64; ++t) {
      u64_t cand = sk[t];
      if (cand > th) {
        insert_step(key, cand, lane);
        th = shfl_u64(key, 15);
      }
    }
    if (lane < 16) {
      uint_t idx = 0xFFFFFFFFu - (uint_t)key;
      uint_t us = (uint_t)(key >> 32);
      us = (us & 0x80000000u) ? (us & 0x7FFFFFFFu) : ~us;   // decode score
      out[(size_t)b * KTOP + lane] = __uint_as_float(us) - log_w[idx];
    }
  }
}

// ------------------------------------------------------------------
extern "C" void kernel_launch(void* const* d_in, const int* in_sizes, int n_in,
                              void* d_out, int out_size, void* d_ws, size_t ws_size,
                              hipStream_t stream) {
  const float* x     = (const float*)d_in[0];
  const float* log_w = (const float*)d_in[1];
  const float* z     = (const float*)d_in[2];
  const float* W1    = (const float*)d_in[3];
  const float* b1    = (const float*)d_in[4];
  const float* W2    = (const float*)d_in[5];
  const float* b2    = (const float*)d_in[6];
  float* out = (float*)d_out;

  char* p = (char*)d_ws;
  float* sc     = (float*)p;                                   // 64MB (G3 out)
  ushort_t* rawb= (ushort_t*)p;                                // 32MB, aliases
                 // sc's first half: G2 writes rawb -> params reads it ->
                 // G3 overwrites the region with sc. Stream-ordered, safe.
  p += (size_t)BROWS * NCOMP * 4;
  float* cw    = (float*)p;    p += (size_t)NCOMP * 4;
  ushort_t* Ps = (ushort_t*)p; p += (size_t)NCOMP * 1024 * 2;  // 64MB
  ushort_t* h16= (ushort_t*)p; p += (size_t)NCOMP * 512 * 2;   // 32MB
  ushort_t* z16= (ushort_t*)p; p += (size_t)NCOMP * 128 * 2;   // 8MB
  ushort_t* W1t= (ushort_t*)p; p += (size_t)512 * 128 * 2;
  ushort_t* W2t= (ushort_t*)p; p += (size_t)512 * 512 * 2;
  ushort_t* Xs = (ushort_t*)p; p += (size_t)512 * 512 * 2;

  // prep (merged): z16, W1t, W2t, Xs
  hipLaunchKernelGGL(prep_kernel, dim3(5888), dim3(256), 0, stream,
                     x, z, W1, W2, z16, W1t, W2t, Xs);

  // G1: h16 = relu(z16 @ W1t^T + b1)   [32768,128] x [512,128]^T
  hipLaunchKernelGGL((gemm256<0>), dim3(256), dim3(512), 0, stream,
                     z16, LDIM, W1t, LDIM, b1, h16, HDIM,
                     2, 2, 0, 0, 0, 0, 0, 0, 2, 0);
  // G2: rawb = h16 @ W2t^T + b2  -> bf16 out (halves write + params read)
  hipLaunchKernelGGL((gemm256<3>), dim3(256), dim3(512), 0, stream,
                     h16, HDIM, W2t, HDIM, b2, rawb, HDIM,
                     8, 8, 0, 0, 0, 0, 0, 0, 2, 0);
  // params: rawb (bf16) -> Ps (split hi/lo), cw = cvec + log_w
  hipLaunchKernelGGL(params_kernel, dim3(NCOMP / 4), dim3(256), 0, stream,
                     rawb, log_w, Ps, cw);
  // G3: sc = Xs @ Ps^T + cw  (split-bf16, A-lo dropped: uh*vh + uh*vl)
  //     K=1024: A segs {0,0} (hi,hi); B segs {0,512} (hi,lo); nt=16
  hipLaunchKernelGGL((gemm256<1>), dim3(256), dim3(512), 0, stream,
                     Xs, 512, Ps, 1024, cw, sc, NCOMP,
                     16, 8, 0, 0, 0, 0, 512, 0, 2, 1);
  // topk over scores; output lp = score - log_w[idx]
  hipLaunchKernelGGL(topk_kernel, dim3(BROWS), dim3(256), 0, stream, sc, log_w, out);
}

// Round 18
// 192.287 us; speedup vs baseline: 1.2546x; 1.0238x over previous
//
#include <hip/hip_runtime.h>
#include <math.h>

#define NCOMP 32768
#define LDIM  128
#define HDIM  512
#define DDIM  256
#define BROWS 512
#define KTOP  16

// -0.5 * D * log(2*pi)
#define NEG_HALF_D_LOG2PI (-235.24844f)

typedef short bf16x8 __attribute__((ext_vector_type(8)));
typedef float f32x4  __attribute__((ext_vector_type(4)));
typedef unsigned short ushort_t;
typedef unsigned int uint_t;
typedef unsigned long long u64_t;

// ---------------- bf16 helpers (RNE) ----------------
__device__ __forceinline__ ushort_t f2bf(float f) {
  uint_t u = __float_as_uint(f);
  u = u + 0x7fffu + ((u >> 16) & 1u);
  return (ushort_t)(u >> 16);
}
__device__ __forceinline__ float bf2f(ushort_t h) {
  return __uint_as_float(((uint_t)h) << 16);
}

// async global->LDS, 16B per lane. LDS dest is wave-uniform base + lane*16.
__device__ __forceinline__ void load_lds16(const ushort_t* g, ushort_t* l) {
  __builtin_amdgcn_global_load_lds(
      (const __attribute__((address_space(1))) unsigned int*)g,
      (__attribute__((address_space(3))) unsigned int*)l, 16, 0, 0);
}

// ------------------------------------------------------------------
// Merged prep kernel (proven r11). Block ranges:
//  [0,4096)     cast z -> z16 bf16
//  [4096,4352)  W1 [128][512] -> W1t [512][128] bf16
//  [4352,5376)  W2 [512][512] -> W2t [512][512] bf16
//  [5376,5888)  x -> Xs [512][512] bf16: [x^2 (256) | x (256)]
// ------------------------------------------------------------------
__global__ __launch_bounds__(256) void prep_kernel(
    const float* __restrict__ x, const float* __restrict__ z,
    const float* __restrict__ W1, const float* __restrict__ W2,
    ushort_t* __restrict__ z16, ushort_t* __restrict__ W1t,
    ushort_t* __restrict__ W2t, ushort_t* __restrict__ Xs) {
  const int blk = blockIdx.x, tid = threadIdx.x;
  if (blk < 4096) {
    int i = (blk * 256 + tid) * 4;
    float4 v = *(const float4*)&z[i];
    z16[i + 0] = f2bf(v.x);
    z16[i + 1] = f2bf(v.y);
    z16[i + 2] = f2bf(v.z);
    z16[i + 3] = f2bf(v.w);
  } else if (blk < 4352) {
    int i = (blk - 4096) * 256 + tid;      // 128*512
    int r = i >> 9, c = i & 511;
    W1t[(size_t)c * 128 + r] = f2bf(W1[i]);
  } else if (blk < 5376) {
    int i = (blk - 4352) * 256 + tid;      // 512*512
    int r = i >> 9, c = i & 511;
    W2t[(size_t)c * 512 + r] = f2bf(W2[i]);
  } else {
    int i = (blk - 5376) * 256 + tid;      // 512*256
    int b = i >> 8, d = i & 255;
    float xv = x[i];
    size_t base = (size_t)b * 512;
    Xs[base + d]       = f2bf(xv * xv);
    Xs[base + 256 + d] = f2bf(xv);
  }
}

// rawb [N][512] bf16 (mu | logvar) -> Ps [N][1024] bf16 : [hi(v) | lo(v)],
// v = [-0.5*inv_var (256), mu*inv_var (256)], plus
// cw[n] = cvec[n] + log_w[n]  (G3's bias -> G3 emits SCORES directly).
__global__ __launch_bounds__(256) void params_kernel(const ushort_t* __restrict__ rawb,
                                                     const float* __restrict__ log_w,
                                                     ushort_t* __restrict__ Ps,
                                                     float* __restrict__ cw) {
  const int w = threadIdx.x >> 6, lane = threadIdx.x & 63;
  const int n = blockIdx.x * 4 + w;
  size_t rb = (size_t)n * 512;
  ushort4 mu4 = *(const ushort4*)(rawb + rb + lane * 4);
  ushort4 lv4 = *(const ushort4*)(rawb + rb + 256 + lane * 4);
  float mus[4] = {bf2f(mu4.x), bf2f(mu4.y), bf2f(mu4.z), bf2f(mu4.w)};
  float lvs[4] = {bf2f(lv4.x), bf2f(lv4.y), bf2f(lv4.z), bf2f(lv4.w)};
  ushort4 o0, o1, o2, o3;
  ushort_t* p0 = &o0.x; ushort_t* p1 = &o1.x;
  ushort_t* p2 = &o2.x; ushort_t* p3 = &o3.x;
  float part = 0.f;
  #pragma unroll
  for (int e = 0; e < 4; e++) {
    float lv = lvs[e];
    float sp = (lv > 20.f) ? lv : log1pf(expf(lv));
    float sd = fminf(sp + 0.1f, 1.0f);
    float iv = 1.0f / (sd * sd);
    float v0 = -0.5f * iv;
    float v1 = mus[e] * iv;
    ushort_t h0 = f2bf(v0), h1 = f2bf(v1);
    p0[e] = h0; p1[e] = h1;
    p2[e] = f2bf(v0 - bf2f(h0));
    p3[e] = f2bf(v1 - bf2f(h1));
    part += -0.5f * mus[e] * mus[e] * iv - logf(sd);
  }
  size_t pb = (size_t)n * 1024;
  *(ushort4*)(Ps + pb + lane * 4)       = o0;
  *(ushort4*)(Ps + pb + 256 + lane * 4) = o1;
  *(ushort4*)(Ps + pb + 512 + lane * 4) = o2;
  *(ushort4*)(Ps + pb + 768 + lane * 4) = o3;
  #pragma unroll
  for (int off = 32; off > 0; off >>= 1) part += __shfl_down(part, off, 64);
  if (lane == 0) cw[n] = part + NEG_HALF_D_LOG2PI + log_w[n];
}

// ------------------------------------------------------------------
// 256x256 bf16 MFMA GEMM — r11/r14 2-phase structure (proven optimum:
// r7 8-phase -35%, r12 BK=32 -14%, r13 asym-depth -19%, r15 128^2 -38%).
// BK=64, 512 threads (8 waves 2x4), double-buffered 128KB LDS,
// global_load_lds 16B with pre-swizzled source, XOR swizzle, k-half
// composed via XOR. One __syncthreads per K-step.
// EPI: 0 = relu(+bias) -> bf16; 1 = +bias -> f32; 3 = +bias -> bf16
// ------------------------------------------------------------------
template<int EPI>
__global__ __launch_bounds__(512, 2) void gemm256(
    const ushort_t* __restrict__ A, int lda,
    const ushort_t* __restrict__ B, int ldb,
    const float* __restrict__ bias,
    void* __restrict__ Cout, int ldc,
    int nsteps, int sps,
    int kbA0, int kbA1, int kbA2,
    int kbB0, int kbB1, int kbB2,
    int nShort, int shortIsM) {
  __shared__ __align__(16) ushort_t As[2][16384];   // 32KB per buffer
  __shared__ __align__(16) ushort_t Bs[2][16384];

  const int tid = threadIdx.x;
  const int lane = tid & 63, wid = tid >> 6;
  const int wr = wid >> 2, wc = wid & 3;            // 2 x 4 wave grid

  // XCD-chunked bijective block swizzle (gridDim.x % 8 == 0)
  const int cpx = gridDim.x >> 3;
  const int newid = (blockIdx.x & 7) * cpx + (blockIdx.x >> 3);
  const int s = newid % nShort, l = newid / nShort;
  const int m0 = (shortIsM ? s : l) * 256;
  const int n0 = (shortIsM ? l : s) * 256;

  // ---- staging: 4 rounds per matrix; dest chunk p = r*512+tid (16B) ----
  const ushort_t* pA[4];
  const ushort_t* pB[4];
  #pragma unroll
  for (int r = 0; r < 4; r++) {
    int p = r * 512 + tid;
    int row = p >> 3;
    int col = ((p & 7) ^ (row & 7)) * 8;
    pA[r] = A + (size_t)(m0 + row) * lda + col;
    pB[r] = B + (size_t)(n0 + row) * ldb + col;
  }

  // ---- fragment read byte-offsets (swizzled); k-half composed via XOR ----
  int aoff[8], boff[4];
  #pragma unroll
  for (int i = 0; i < 8; i++) {
    int ra = wr * 128 + i * 16 + (lane & 15);
    aoff[i] = (ra * 128 + ((lane >> 4) * 16)) ^ ((ra & 7) << 4);
  }
  #pragma unroll
  for (int j = 0; j < 4; j++) {
    int rb = wc * 64 + j * 16 + (lane & 15);
    boff[j] = (rb * 128 + ((lane >> 4) * 16)) ^ ((rb & 7) << 4);
  }

  f32x4 acc[8][4];
  #pragma unroll
  for (int i = 0; i < 8; i++)
    #pragma unroll
    for (int j = 0; j < 4; j++)
      acc[i][j] = (f32x4){0.f, 0.f, 0.f, 0.f};

  auto stage = [&](int buf, int step) {
    int sg = (step >= sps) ? ((step >= 2 * sps) ? 2 : 1) : 0;
    int ks = (step - sg * sps) << 6;
    int kA = ((sg == 0) ? kbA0 : (sg == 1) ? kbA1 : kbA2) + ks;
    int kB = ((sg == 0) ? kbB0 : (sg == 1) ? kbB1 : kbB2) + ks;
    #pragma unroll
    for (int r = 0; r < 4; r++) {
      load_lds16(pA[r] + kA, &As[buf][(r * 512 + tid) * 8]);
      load_lds16(pB[r] + kB, &Bs[buf][(r * 512 + tid) * 8]);
    }
  };

  stage(0, 0);
  __syncthreads();              // vmcnt drain -> buf0 ready

  int cur = 0;
  for (int step = 0; step < nsteps; ++step) {
    if (step + 1 < nsteps) stage(cur ^ 1, step + 1);   // loads fly over compute

    const char* Ab = (const char*)As[cur];
    const char* Bb = (const char*)Bs[cur];
    #pragma unroll
    for (int kh = 0; kh < 2; ++kh) {
      bf16x8 af[8], bfr[4];
      #pragma unroll
      for (int i = 0; i < 8; i++) af[i] = *(const bf16x8*)(Ab + (aoff[i] ^ (kh << 6)));
      #pragma unroll
      for (int j = 0; j < 4; j++) bfr[j] = *(const bf16x8*)(Bb + (boff[j] ^ (kh << 6)));
      #pragma unroll
      for (int i = 0; i < 8; i++)
        #pragma unroll
        for (int j = 0; j < 4; j++)
          acc[i][j] = __builtin_amdgcn_mfma_f32_16x16x32_bf16(af[i], bfr[j], acc[i][j], 0, 0, 0);
    }
    __syncthreads();            // drains vmcnt (next buf ready) + lgkm
    cur ^= 1;
  }

  // ---- epilogue ----
  float bv[4];
  #pragma unroll
  for (int j = 0; j < 4; j++)
    bv[j] = bias[n0 + wc * 64 + j * 16 + (lane & 15)];
  #pragma unroll
  for (int i = 0; i < 8; i++) {
    int rowb = m0 + wr * 128 + i * 16 + ((lane >> 4) << 2);
    #pragma unroll
    for (int r = 0; r < 4; r++) {
      #pragma unroll
      for (int j = 0; j < 4; j++) {
        int col = n0 + wc * 64 + j * 16 + (lane & 15);
        float v = acc[i][j][r] + bv[j];
        if (EPI == 0) {
          v = fmaxf(v, 0.f);
          ((ushort_t*)Cout)[(size_t)(rowb + r) * ldc + col] = f2bf(v);
        } else if (EPI == 3) {
          ((ushort_t*)Cout)[(size_t)(rowb + r) * ldc + col] = f2bf(v);
        } else {
          ((float*)Cout)[(size_t)(rowb + r) * ldc + col] = v;
        }
      }
    }
  }
}

// ------------------------------------------------------------------
// Top-16 over bf16 scores (log_w folded into G3's bias; G3 emits bf16).
// Key = (sortable_u32(bf16score<<16) << 32) | (~idx): bigger = higher
// score, ties -> lower index. Wave-cooperative ballot-filtered select.
// Output decodes the exact bf16 score and subtracts log_w[idx].
// ------------------------------------------------------------------
typedef ushort_t us8 __attribute__((ext_vector_type(8)));

__device__ __forceinline__ u64_t shfl_up1_u64(u64_t v) {
  uint_t lo = (uint_t)v, hi = (uint_t)(v >> 32);
  lo = __shfl_up(lo, 1, 64); hi = __shfl_up(hi, 1, 64);
  return ((u64_t)hi << 32) | lo;
}
__device__ __forceinline__ u64_t shfl_u64(u64_t v, int src) {
  uint_t lo = (uint_t)v, hi = (uint_t)(v >> 32);
  lo = __shfl(lo, src, 64); hi = __shfl(hi, src, 64);
  return ((u64_t)hi << 32) | lo;
}
__device__ __forceinline__ void insert_step(u64_t& key, u64_t cand, int lane) {
  u64_t kup = shfl_up1_u64(key);
  if (lane == 0) kup = ~0ULL;
  if (cand > key) key = (cand > kup) ? kup : cand;
}

__global__ __launch_bounds__(256) void topk_kernel(const ushort_t* __restrict__ scb,
                                                   const float* __restrict__ log_w,
                                                   float* __restrict__ out) {
  const int b = blockIdx.x;
  const int tid = threadIdx.x;
  const int w = tid >> 6, lane = tid & 63;
  const ushort_t* row = scb + (size_t)b * NCOMP;

  u64_t key = 0;
  u64_t theta = 0;

  const int base = w * 8192;
  us8 s8 = *(const us8*)&row[base + lane * 8];
  for (int c = 0; c < 16; ++c) {
    us8 cur = s8;
    int n0 = base + c * 512 + lane * 8;
    if (c + 1 < 16) s8 = *(const us8*)&row[n0 + 512];   // prefetch
    #pragma unroll
    for (int e = 0; e < 8; e++) {
      uint_t u = ((uint_t)(ushort_t)cur[e]) << 16;
      u = (u & 0x80000000u) ? ~u : (u | 0x80000000u);
      u64_t k = ((u64_t)u << 32) | (u64_t)(0xFFFFFFFFu - (uint_t)(n0 + e));
      u64_t m = __ballot(k > theta);
      if (m) {
        do {
          int src = __ffsll((long long)m) - 1;
          m &= m - 1;
          u64_t cand = shfl_u64(k, src);
          insert_step(key, cand, lane);
        } while (m);
        theta = shfl_u64(key, 15);
      }
    }
  }

  __shared__ u64_t sk[64];
  if (lane < 16) sk[w * 16 + lane] = key;
  __syncthreads();
  if (w == 0) {
    u64_t th = shfl_u64(key, 15);
    for (int t = 16; t < 64; ++t) {
      u64_t cand = sk[t];
      if (cand > th) {
        insert_step(key, cand, lane);
        th = shfl_u64(key, 15);
      }
    }
    if (lane < 16) {
      uint_t idx = 0xFFFFFFFFu - (uint_t)key;
      uint_t us = (uint_t)(key >> 32);
      us = (us & 0x80000000u) ? (us & 0x7FFFFFFFu) : ~us;   // decode score
      out[(size_t)b * KTOP + lane] = __uint_as_float(us) - log_w[idx];
    }
  }
}

// ------------------------------------------------------------------
extern "C" void kernel_launch(void* const* d_in, const int* in_sizes, int n_in,
                              void* d_out, int out_size, void* d_ws, size_t ws_size,
                              hipStream_t stream) {
  const float* x     = (const float*)d_in[0];
  const float* log_w = (const float*)d_in[1];
  const float* z     = (const float*)d_in[2];
  const float* W1    = (const float*)d_in[3];
  const float* b1    = (const float*)d_in[4];
  const float* W2    = (const float*)d_in[5];
  const float* b2    = (const float*)d_in[6];
  float* out = (float*)d_out;

  char* p = (char*)d_ws;
  ushort_t* scb = (ushort_t*)p;                               // 32MB (G3 out, bf16)
  ushort_t* rawb= (ushort_t*)p;                               // 32MB, same region:
                 // G2 writes rawb -> params reads it -> G3 overwrites with scb.
  p += (size_t)BROWS * NCOMP * 4;                             // keep 64MB reserved
  float* cw    = (float*)p;    p += (size_t)NCOMP * 4;
  ushort_t* Ps = (ushort_t*)p; p += (size_t)NCOMP * 1024 * 2; // 64MB
  ushort_t* h16= (ushort_t*)p; p += (size_t)NCOMP * 512 * 2;  // 32MB
  ushort_t* z16= (ushort_t*)p; p += (size_t)NCOMP * 128 * 2;  // 8MB
  ushort_t* W1t= (ushort_t*)p; p += (size_t)512 * 128 * 2;
  ushort_t* W2t= (ushort_t*)p; p += (size_t)512 * 512 * 2;
  ushort_t* Xs = (ushort_t*)p; p += (size_t)512 * 512 * 2;

  // prep (merged): z16, W1t, W2t, Xs
  hipLaunchKernelGGL(prep_kernel, dim3(5888), dim3(256), 0, stream,
                     x, z, W1, W2, z16, W1t, W2t, Xs);

  // G1: h16 = relu(z16 @ W1t^T + b1)   [32768,128] x [512,128]^T
  hipLaunchKernelGGL((gemm256<0>), dim3(256), dim3(512), 0, stream,
                     z16, LDIM, W1t, LDIM, b1, h16, HDIM,
                     2, 2, 0, 0, 0, 0, 0, 0, 2, 0);
  // G2: rawb = h16 @ W2t^T + b2  -> bf16 out
  hipLaunchKernelGGL((gemm256<3>), dim3(256), dim3(512), 0, stream,
                     h16, HDIM, W2t, HDIM, b2, rawb, HDIM,
                     8, 8, 0, 0, 0, 0, 0, 0, 2, 0);
  // params: rawb (bf16) -> Ps (split hi/lo), cw = cvec + log_w
  hipLaunchKernelGGL(params_kernel, dim3(NCOMP / 4), dim3(256), 0, stream,
                     rawb, log_w, Ps, cw);
  // G3: scb = bf16(Xs @ Ps^T + cw)  (split-bf16, A-lo dropped)
  //     K=1024: A segs {0,0} (hi,hi); B segs {0,512} (hi,lo); nt=16
  hipLaunchKernelGGL((gemm256<3>), dim3(256), dim3(512), 0, stream,
                     Xs, 512, Ps, 1024, cw, scb, NCOMP,
                     16, 8, 0, 0, 0, 0, 512, 0, 2, 1);
  // topk over bf16 scores; output lp = score - log_w[idx]
  hipLaunchKernelGGL(topk_kernel, dim3(BROWS), dim3(256), 0, stream, scb, log_w, out);
}

// Round 19
// 167.733 us; speedup vs baseline: 1.4382x; 1.1464x over previous
//
#include <hip/hip_runtime.h>
#include <math.h>

#define NCOMP 32768
#define LDIM  128
#define HDIM  512
#define DDIM  256
#define BROWS 512
#define KTOP  16

// -0.5 * D * log(2*pi)
#define NEG_HALF_D_LOG2PI (-235.24844f)

typedef short bf16x8 __attribute__((ext_vector_type(8)));
typedef float f32x4  __attribute__((ext_vector_type(4)));
typedef unsigned short ushort_t;
typedef unsigned int uint_t;
typedef unsigned long long u64_t;

// ---------------- bf16 helpers (RNE) ----------------
__device__ __forceinline__ ushort_t f2bf(float f) {
  uint_t u = __float_as_uint(f);
  u = u + 0x7fffu + ((u >> 16) & 1u);
  return (ushort_t)(u >> 16);
}
__device__ __forceinline__ float bf2f(ushort_t h) {
  return __uint_as_float(((uint_t)h) << 16);
}

// async global->LDS, 16B per lane. LDS dest is wave-uniform base + lane*16.
__device__ __forceinline__ void load_lds16(const ushort_t* g, ushort_t* l) {
  __builtin_amdgcn_global_load_lds(
      (const __attribute__((address_space(1))) unsigned int*)g,
      (__attribute__((address_space(3))) unsigned int*)l, 16, 0, 0);
}

// ------------------------------------------------------------------
// Merged prep kernel (proven r11). Block ranges:
//  [0,4096)     cast z -> z16 bf16
//  [4096,4352)  W1 [128][512] -> W1t [512][128] bf16
//  [4352,5376)  W2 [512][512] -> W2t [512][512] bf16
//  [5376,5888)  x -> Xs [512][512] bf16: [x^2 (256) | x (256)]
// ------------------------------------------------------------------
__global__ __launch_bounds__(256) void prep_kernel(
    const float* __restrict__ x, const float* __restrict__ z,
    const float* __restrict__ W1, const float* __restrict__ W2,
    ushort_t* __restrict__ z16, ushort_t* __restrict__ W1t,
    ushort_t* __restrict__ W2t, ushort_t* __restrict__ Xs) {
  const int blk = blockIdx.x, tid = threadIdx.x;
  if (blk < 4096) {
    int i = (blk * 256 + tid) * 4;
    float4 v = *(const float4*)&z[i];
    z16[i + 0] = f2bf(v.x);
    z16[i + 1] = f2bf(v.y);
    z16[i + 2] = f2bf(v.z);
    z16[i + 3] = f2bf(v.w);
  } else if (blk < 4352) {
    int i = (blk - 4096) * 256 + tid;      // 128*512
    int r = i >> 9, c = i & 511;
    W1t[(size_t)c * 128 + r] = f2bf(W1[i]);
  } else if (blk < 5376) {
    int i = (blk - 4352) * 256 + tid;      // 512*512
    int r = i >> 9, c = i & 511;
    W2t[(size_t)c * 512 + r] = f2bf(W2[i]);
  } else {
    int i = (blk - 5376) * 256 + tid;      // 512*256
    int b = i >> 8, d = i & 255;
    float xv = x[i];
    size_t base = (size_t)b * 512;
    Xs[base + d]       = f2bf(xv * xv);
    Xs[base + 256 + d] = f2bf(xv);
  }
}

// rawb [N][512] bf16 (mu | logvar) -> Ps [N][512] bf16 : hi(v) only,
// v = [-0.5*inv_var (256), mu*inv_var (256)], plus
// cw[n] = cvec[n] + log_w[n]  (G3's bias -> G3 emits SCORES directly).
// B-side lo slab dropped (r19): score = uh*vh + cw; added error
// Sum_d u_d * vlo_d, random-sign over 256 dims ~ 0.1-2 absolute.
__global__ __launch_bounds__(256) void params_kernel(const ushort_t* __restrict__ rawb,
                                                     const float* __restrict__ log_w,
                                                     ushort_t* __restrict__ Ps,
                                                     float* __restrict__ cw) {
  const int w = threadIdx.x >> 6, lane = threadIdx.x & 63;
  const int n = blockIdx.x * 4 + w;
  size_t rb = (size_t)n * 512;
  ushort4 mu4 = *(const ushort4*)(rawb + rb + lane * 4);
  ushort4 lv4 = *(const ushort4*)(rawb + rb + 256 + lane * 4);
  float mus[4] = {bf2f(mu4.x), bf2f(mu4.y), bf2f(mu4.z), bf2f(mu4.w)};
  float lvs[4] = {bf2f(lv4.x), bf2f(lv4.y), bf2f(lv4.z), bf2f(lv4.w)};
  ushort4 o0, o1;
  ushort_t* p0 = &o0.x; ushort_t* p1 = &o1.x;
  float part = 0.f;
  #pragma unroll
  for (int e = 0; e < 4; e++) {
    float lv = lvs[e];
    float sp = (lv > 20.f) ? lv : log1pf(expf(lv));
    float sd = fminf(sp + 0.1f, 1.0f);
    float iv = 1.0f / (sd * sd);
    float v0 = -0.5f * iv;
    float v1 = mus[e] * iv;
    p0[e] = f2bf(v0);
    p1[e] = f2bf(v1);
    part += -0.5f * mus[e] * mus[e] * iv - logf(sd);
  }
  size_t pb = (size_t)n * 512;
  *(ushort4*)(Ps + pb + lane * 4)       = o0;
  *(ushort4*)(Ps + pb + 256 + lane * 4) = o1;
  #pragma unroll
  for (int off = 32; off > 0; off >>= 1) part += __shfl_down(part, off, 64);
  if (lane == 0) cw[n] = part + NEG_HALF_D_LOG2PI + log_w[n];
}

// ------------------------------------------------------------------
// 256x256 bf16 MFMA GEMM — r11/r14 2-phase structure (proven optimum:
// r7 8-phase -35%, r12 BK=32 -14%, r13 asym-depth -19%, r15 128^2 -38%).
// BK=64, 512 threads (8 waves 2x4), double-buffered 128KB LDS,
// global_load_lds 16B with pre-swizzled source, XOR swizzle, k-half
// composed via XOR. One __syncthreads per K-step.
// EPI: 0 = relu(+bias) -> bf16; 1 = +bias -> f32; 3 = +bias -> bf16
// ------------------------------------------------------------------
template<int EPI>
__global__ __launch_bounds__(512, 2) void gemm256(
    const ushort_t* __restrict__ A, int lda,
    const ushort_t* __restrict__ B, int ldb,
    const float* __restrict__ bias,
    void* __restrict__ Cout, int ldc,
    int nsteps, int sps,
    int kbA0, int kbA1, int kbA2,
    int kbB0, int kbB1, int kbB2,
    int nShort, int shortIsM) {
  __shared__ __align__(16) ushort_t As[2][16384];   // 32KB per buffer
  __shared__ __align__(16) ushort_t Bs[2][16384];

  const int tid = threadIdx.x;
  const int lane = tid & 63, wid = tid >> 6;
  const int wr = wid >> 2, wc = wid & 3;            // 2 x 4 wave grid

  // XCD-chunked bijective block swizzle (gridDim.x % 8 == 0)
  const int cpx = gridDim.x >> 3;
  const int newid = (blockIdx.x & 7) * cpx + (blockIdx.x >> 3);
  const int s = newid % nShort, l = newid / nShort;
  const int m0 = (shortIsM ? s : l) * 256;
  const int n0 = (shortIsM ? l : s) * 256;

  // ---- staging: 4 rounds per matrix; dest chunk p = r*512+tid (16B) ----
  const ushort_t* pA[4];
  const ushort_t* pB[4];
  #pragma unroll
  for (int r = 0; r < 4; r++) {
    int p = r * 512 + tid;
    int row = p >> 3;
    int col = ((p & 7) ^ (row & 7)) * 8;
    pA[r] = A + (size_t)(m0 + row) * lda + col;
    pB[r] = B + (size_t)(n0 + row) * ldb + col;
  }

  // ---- fragment read byte-offsets (swizzled); k-half composed via XOR ----
  int aoff[8], boff[4];
  #pragma unroll
  for (int i = 0; i < 8; i++) {
    int ra = wr * 128 + i * 16 + (lane & 15);
    aoff[i] = (ra * 128 + ((lane >> 4) * 16)) ^ ((ra & 7) << 4);
  }
  #pragma unroll
  for (int j = 0; j < 4; j++) {
    int rb = wc * 64 + j * 16 + (lane & 15);
    boff[j] = (rb * 128 + ((lane >> 4) * 16)) ^ ((rb & 7) << 4);
  }

  f32x4 acc[8][4];
  #pragma unroll
  for (int i = 0; i < 8; i++)
    #pragma unroll
    for (int j = 0; j < 4; j++)
      acc[i][j] = (f32x4){0.f, 0.f, 0.f, 0.f};

  auto stage = [&](int buf, int step) {
    int sg = (step >= sps) ? ((step >= 2 * sps) ? 2 : 1) : 0;
    int ks = (step - sg * sps) << 6;
    int kA = ((sg == 0) ? kbA0 : (sg == 1) ? kbA1 : kbA2) + ks;
    int kB = ((sg == 0) ? kbB0 : (sg == 1) ? kbB1 : kbB2) + ks;
    #pragma unroll
    for (int r = 0; r < 4; r++) {
      load_lds16(pA[r] + kA, &As[buf][(r * 512 + tid) * 8]);
      load_lds16(pB[r] + kB, &Bs[buf][(r * 512 + tid) * 8]);
    }
  };

  stage(0, 0);
  __syncthreads();              // vmcnt drain -> buf0 ready

  int cur = 0;
  for (int step = 0; step < nsteps; ++step) {
    if (step + 1 < nsteps) stage(cur ^ 1, step + 1);   // loads fly over compute

    const char* Ab = (const char*)As[cur];
    const char* Bb = (const char*)Bs[cur];
    #pragma unroll
    for (int kh = 0; kh < 2; ++kh) {
      bf16x8 af[8], bfr[4];
      #pragma unroll
      for (int i = 0; i < 8; i++) af[i] = *(const bf16x8*)(Ab + (aoff[i] ^ (kh << 6)));
      #pragma unroll
      for (int j = 0; j < 4; j++) bfr[j] = *(const bf16x8*)(Bb + (boff[j] ^ (kh << 6)));
      #pragma unroll
      for (int i = 0; i < 8; i++)
        #pragma unroll
        for (int j = 0; j < 4; j++)
          acc[i][j] = __builtin_amdgcn_mfma_f32_16x16x32_bf16(af[i], bfr[j], acc[i][j], 0, 0, 0);
    }
    __syncthreads();            // drains vmcnt (next buf ready) + lgkm
    cur ^= 1;
  }

  // ---- epilogue ----
  float bv[4];
  #pragma unroll
  for (int j = 0; j < 4; j++)
    bv[j] = bias[n0 + wc * 64 + j * 16 + (lane & 15)];
  #pragma unroll
  for (int i = 0; i < 8; i++) {
    int rowb = m0 + wr * 128 + i * 16 + ((lane >> 4) << 2);
    #pragma unroll
    for (int r = 0; r < 4; r++) {
      #pragma unroll
      for (int j = 0; j < 4; j++) {
        int col = n0 + wc * 64 + j * 16 + (lane & 15);
        float v = acc[i][j][r] + bv[j];
        if (EPI == 0) {
          v = fmaxf(v, 0.f);
          ((ushort_t*)Cout)[(size_t)(rowb + r) * ldc + col] = f2bf(v);
        } else if (EPI == 3) {
          ((ushort_t*)Cout)[(size_t)(rowb + r) * ldc + col] = f2bf(v);
        } else {
          ((float*)Cout)[(size_t)(rowb + r) * ldc + col] = v;
        }
      }
    }
  }
}

// ------------------------------------------------------------------
// Top-16 over bf16 scores (log_w folded into G3's bias; G3 emits bf16).
// Key = (sortable_u32(bf16score<<16) << 32) | (~idx): bigger = higher
// score, ties -> lower index. Wave-cooperative ballot-filtered select.
// Output decodes the exact bf16 score and subtracts log_w[idx].
// ------------------------------------------------------------------
typedef ushort_t us8 __attribute__((ext_vector_type(8)));

__device__ __forceinline__ u64_t shfl_up1_u64(u64_t v) {
  uint_t lo = (uint_t)v, hi = (uint_t)(v >> 32);
  lo = __shfl_up(lo, 1, 64); hi = __shfl_up(hi, 1, 64);
  return ((u64_t)hi << 32) | lo;
}
__device__ __forceinline__ u64_t shfl_u64(u64_t v, int src) {
  uint_t lo = (uint_t)v, hi = (uint_t)(v >> 32);
  lo = __shfl(lo, src, 64); hi = __shfl(hi, src, 64);
  return ((u64_t)hi << 32) | lo;
}
__device__ __forceinline__ void insert_step(u64_t& key, u64_t cand, int lane) {
  u64_t kup = shfl_up1_u64(key);
  if (lane == 0) kup = ~0ULL;
  if (cand > key) key = (cand > kup) ? kup : cand;
}

__global__ __launch_bounds__(256) void topk_kernel(const ushort_t* __restrict__ scb,
                                                   const float* __restrict__ log_w,
                                                   float* __restrict__ out) {
  const int b = blockIdx.x;
  const int tid = threadIdx.x;
  const int w = tid >> 6, lane = tid & 63;
  const ushort_t* row = scb + (size_t)b * NCOMP;

  u64_t key = 0;
  u64_t theta = 0;

  const int base = w * 8192;
  us8 s8 = *(const us8*)&row[base + lane * 8];
  for (int c = 0; c < 16; ++c) {
    us8 cur = s8;
    int n0 = base + c * 512 + lane * 8;
    if (c + 1 < 16) s8 = *(const us8*)&row[n0 + 512];   // prefetch
    #pragma unroll
    for (int e = 0; e < 8; e++) {
      uint_t u = ((uint_t)(ushort_t)cur[e]) << 16;
      u = (u & 0x80000000u) ? ~u : (u | 0x80000000u);
      u64_t k = ((u64_t)u << 32) | (u64_t)(0xFFFFFFFFu - (uint_t)(n0 + e));
      u64_t m = __ballot(k > theta);
      if (m) {
        do {
          int src = __ffsll((long long)m) - 1;
          m &= m - 1;
          u64_t cand = shfl_u64(k, src);
          insert_step(key, cand, lane);
        } while (m);
        theta = shfl_u64(key, 15);
      }
    }
  }

  __shared__ u64_t sk[64];
  if (lane < 16) sk[w * 16 + lane] = key;
  __syncthreads();
  if (w == 0) {
    u64_t th = shfl_u64(key, 15);
    for (int t = 16; t < 64; ++t) {
      u64_t cand = sk[t];
      if (cand > th) {
        insert_step(key, cand, lane);
        th = shfl_u64(key, 15);
      }
    }
    if (lane < 16) {
      uint_t idx = 0xFFFFFFFFu - (uint_t)key;
      uint_t us = (uint_t)(key >> 32);
      us = (us & 0x80000000u) ? (us & 0x7FFFFFFFu) : ~us;   // decode score
      out[(size_t)b * KTOP + lane] = __uint_as_float(us) - log_w[idx];
    }
  }
}

// ------------------------------------------------------------------
extern "C" void kernel_launch(void* const* d_in, const int* in_sizes, int n_in,
                              void* d_out, int out_size, void* d_ws, size_t ws_size,
                              hipStream_t stream) {
  const float* x     = (const float*)d_in[0];
  const float* log_w = (const float*)d_in[1];
  const float* z     = (const float*)d_in[2];
  const float* W1    = (const float*)d_in[3];
  const float* b1    = (const float*)d_in[4];
  const float* W2    = (const float*)d_in[5];
  const float* b2    = (const float*)d_in[6];
  float* out = (float*)d_out;

  char* p = (char*)d_ws;
  ushort_t* scb = (ushort_t*)p;                               // 32MB (G3 out, bf16)
  ushort_t* rawb= (ushort_t*)p;                               // 32MB, same region:
                 // G2 writes rawb -> params reads it -> G3 overwrites with scb.
  p += (size_t)BROWS * NCOMP * 4;                             // keep 64MB reserved
  float* cw    = (float*)p;    p += (size_t)NCOMP * 4;
  ushort_t* Ps = (ushort_t*)p; p += (size_t)NCOMP * 512 * 2;  // 32MB (hi only)
  ushort_t* h16= (ushort_t*)p; p += (size_t)NCOMP * 512 * 2;  // 32MB
  ushort_t* z16= (ushort_t*)p; p += (size_t)NCOMP * 128 * 2;  // 8MB
  ushort_t* W1t= (ushort_t*)p; p += (size_t)512 * 128 * 2;
  ushort_t* W2t= (ushort_t*)p; p += (size_t)512 * 512 * 2;
  ushort_t* Xs = (ushort_t*)p; p += (size_t)512 * 512 * 2;

  // prep (merged): z16, W1t, W2t, Xs
  hipLaunchKernelGGL(prep_kernel, dim3(5888), dim3(256), 0, stream,
                     x, z, W1, W2, z16, W1t, W2t, Xs);

  // G1: h16 = relu(z16 @ W1t^T + b1)   [32768,128] x [512,128]^T
  hipLaunchKernelGGL((gemm256<0>), dim3(256), dim3(512), 0, stream,
                     z16, LDIM, W1t, LDIM, b1, h16, HDIM,
                     2, 2, 0, 0, 0, 0, 0, 0, 2, 0);
  // G2: rawb = h16 @ W2t^T + b2  -> bf16 out
  hipLaunchKernelGGL((gemm256<3>), dim3(256), dim3(512), 0, stream,
                     h16, HDIM, W2t, HDIM, b2, rawb, HDIM,
                     8, 8, 0, 0, 0, 0, 0, 0, 2, 0);
  // params: rawb (bf16) -> Ps (hi only), cw = cvec + log_w
  hipLaunchKernelGGL(params_kernel, dim3(NCOMP / 4), dim3(256), 0, stream,
                     rawb, log_w, Ps, cw);
  // G3: scb = bf16(Xs @ Ps^T + cw)   K=512 single segment, nt=8
  hipLaunchKernelGGL((gemm256<3>), dim3(256), dim3(512), 0, stream,
                     Xs, 512, Ps, 512, cw, scb, NCOMP,
                     8, 8, 0, 0, 0, 0, 0, 0, 2, 1);
  // topk over bf16 scores; output lp = score - log_w[idx]
  hipLaunchKernelGGL(topk_kernel, dim3(BROWS), dim3(256), 0, stream, scb, log_w, out);
}